// Round 16
// baseline (438.915 us; speedup 1.0000x reference)
//
#include <hip/hip_runtime.h>
#include <cstdint>
#include <cstddef>

#define D_DIM 256
#define NT 64            // codes per sweep tile
#define SROWS 128        // rows per sweep block (4 waves x 32 rows, rt=2)
#define SNS 4            // K splits in sweep (grid = 256*4 = 1024)
#define MARGIN 1.3e-3f   // worst-case 2*eps bf16 bound (both-sided)
#define RCAP 2048        // resolve candidate list capacity per block

typedef unsigned int u32;
typedef unsigned short u16;
typedef unsigned long long u64;
typedef __attribute__((ext_vector_type(8))) short s16x8;
typedef __attribute__((ext_vector_type(4))) float f32x4;

static __device__ __forceinline__ u16 f2bf(float f) {
  u32 u = __float_as_uint(f);
  return (u16)((u + 0x7FFFu + ((u >> 16) & 1u)) >> 16);
}

// numpy pairwise_sum block for n=128 (bit-identical to rounds 6-15)
static __device__ __forceinline__ float np_pw128_sq(const float* __restrict__ p) {
  float r0, r1, r2, r3, r4, r5, r6, r7;
  {
    const float4 a = *reinterpret_cast<const float4*>(p);
    const float4 b = *reinterpret_cast<const float4*>(p + 4);
    r0 = __fmul_rn(a.x, a.x); r1 = __fmul_rn(a.y, a.y);
    r2 = __fmul_rn(a.z, a.z); r3 = __fmul_rn(a.w, a.w);
    r4 = __fmul_rn(b.x, b.x); r5 = __fmul_rn(b.y, b.y);
    r6 = __fmul_rn(b.z, b.z); r7 = __fmul_rn(b.w, b.w);
  }
  #pragma unroll
  for (int i = 8; i < 128; i += 8) {
    const float4 a = *reinterpret_cast<const float4*>(p + i);
    const float4 b = *reinterpret_cast<const float4*>(p + i + 4);
    r0 = __fadd_rn(r0, __fmul_rn(a.x, a.x));
    r1 = __fadd_rn(r1, __fmul_rn(a.y, a.y));
    r2 = __fadd_rn(r2, __fmul_rn(a.z, a.z));
    r3 = __fadd_rn(r3, __fmul_rn(a.w, a.w));
    r4 = __fadd_rn(r4, __fmul_rn(b.x, b.x));
    r5 = __fadd_rn(r5, __fmul_rn(b.y, b.y));
    r6 = __fadd_rn(r6, __fmul_rn(b.z, b.z));
    r7 = __fadd_rn(r7, __fmul_rn(b.w, b.w));
  }
  const float s01 = __fadd_rn(r0, r1);
  const float s23 = __fadd_rn(r2, r3);
  const float s45 = __fadd_rn(r4, r5);
  const float s67 = __fadd_rn(r6, r7);
  return __fadd_rn(__fadd_rn(s01, s23), __fadd_rn(s45, s67));
}

// exact r6-chain dot (sequential-d fmaf, bit-identical)
static __device__ __forceinline__ float exact_dot256(
    const float* __restrict__ xp, const float* __restrict__ wp) {
  float a = 0.f;
  #pragma unroll 8
  for (int d4 = 0; d4 < 64; ++d4) {
    const float4 xv = *reinterpret_cast<const float4*>(xp + d4 * 4);
    const float4 wv = *reinterpret_cast<const float4*>(wp + d4 * 4);
    a = fmaf(xv.x, wv.x, a);
    a = fmaf(xv.y, wv.y, a);
    a = fmaf(xv.z, wv.z, a);
    a = fmaf(xv.w, wv.w, a);
  }
  return a;
}

// ---- K0: f32 -> bf16 stash, W only (X is converted in-sweep now) ----
__global__ __launch_bounds__(256) void cvtW_kernel(
    const float* __restrict__ W, u16* __restrict__ Wb, int nw4) {
  const int tid = blockIdx.x * blockDim.x + threadIdx.x;
  const int stride = gridDim.x * blockDim.x;
  for (int g = tid; g < nw4; g += stride) {
    const float4 v = reinterpret_cast<const float4*>(W)[g];
    ushort4 o; o.x = f2bf(v.x); o.y = f2bf(v.y); o.z = f2bf(v.z); o.w = f2bf(v.w);
    reinterpret_cast<ushort4*>(Wb)[g] = o;
  }
}

// 16-lane (DPP row) max-reduce of (v, idx), ties -> lower idx. VALU-only.
#define DPP_RED_STEP(CTRL)                                                     \
  {                                                                            \
    const float ov = __uint_as_float((u32)__builtin_amdgcn_update_dpp(         \
        0, (int)__float_as_uint(v), CTRL, 0xF, 0xF, true));                    \
    const int oi = __builtin_amdgcn_update_dpp(0, idx, CTRL, 0xF, 0xF, true);  \
    if (ov > v || (ov == v && oi < idx)) { v = ov; idx = oi; }                 \
  }

// ---- K1: MFMA sweep, LDS-FREE B path. B-fragments loaded per-lane directly
// from global Wb (2 MB, L2-resident; one 64-code tile = 32 KB = L1-sized and
// shared by the block's 4 waves). No staging, no per-tile barriers -> removes
// the stage/barrier serialization that pinned r10/r13/r15 at ~20% MfmaUtil.
// A-fragments built from f32 X in-register (f2bf, bit-identical to cvt).
// grid = (N/SROWS)*SNS = 1024, block 256.
__global__ __launch_bounds__(256, 3) void vq_sweep(
    const float* __restrict__ X, const u16* __restrict__ Wb,
    float* __restrict__ tm, u16* __restrict__ ti, int K) {
  __shared__ float tmS[SROWS][16];      // 8 KB per-tile top-1 values
  __shared__ u16 tiS[SROWS][16];        // 4 KB per-tile top-1 indices

  const int t = threadIdx.x;
  const int wv = t >> 6;
  const int lane = t & 63;
  const int l15 = lane & 15, lhi = lane >> 4;
  const int rb = blockIdx.x >> 2;      // SNS == 4
  const int hs = blockIdx.x & 3;
  const int row0 = rb * SROWS;
  const int wrow0 = row0 + wv * 32;
  const int c00 = hs * (K / SNS);      // 1024 codes per split

  // A fragments: wave's 32 rows x 256 d, f32 -> bf16 in-register (64 VGPR)
  s16x8 af[2][8];
  #pragma unroll
  for (int rt = 0; rt < 2; ++rt)
    #pragma unroll
    for (int kc = 0; kc < 8; ++kc) {
      const float* xp = X + (size_t)(wrow0 + rt * 16 + l15) * D_DIM + kc * 32 + lhi * 8;
      const float4 a = *reinterpret_cast<const float4*>(xp);
      const float4 b = *reinterpret_cast<const float4*>(xp + 4);
      s16x8 v;
      v[0] = (short)f2bf(a.x); v[1] = (short)f2bf(a.y);
      v[2] = (short)f2bf(a.z); v[3] = (short)f2bf(a.w);
      v[4] = (short)f2bf(b.x); v[5] = (short)f2bf(b.y);
      v[6] = (short)f2bf(b.z); v[7] = (short)f2bf(b.w);
      af[rt][kc] = v;
    }

  const int NTILES = K / SNS / NT;  // 16
  for (int ct = 0; ct < NTILES; ++ct) {
    const int cb = c00 + ct * NT;

    f32x4 acc[2][4];
    #pragma unroll
    for (int rt = 0; rt < 2; ++rt)
      #pragma unroll
      for (int c = 0; c < 4; ++c) acc[rt][c] = f32x4{0.f, 0.f, 0.f, 0.f};

    #pragma unroll
    for (int kc = 0; kc < 8; ++kc) {
      s16x8 bf[4];
      #pragma unroll
      for (int c = 0; c < 4; ++c)
        bf[c] = *reinterpret_cast<const s16x8*>(
            Wb + (size_t)(cb + c * 16 + l15) * D_DIM + kc * 32 + lhi * 8);
      #pragma unroll
      for (int c = 0; c < 4; ++c) {
        acc[0][c] = __builtin_amdgcn_mfma_f32_16x16x32_bf16(af[0][kc], bf[c], acc[0][c], 0, 0, 0);
        acc[1][c] = __builtin_amdgcn_mfma_f32_16x16x32_bf16(af[1][kc], bf[c], acc[1][c], 0, 0, 0);
      }
    }

    // per-row tile-top1 (value, idx): c-reduce in regs, 16-lane DPP reduce
    #pragma unroll
    for (int rt = 0; rt < 2; ++rt)
      #pragma unroll
      for (int r = 0; r < 4; ++r) {
        float v = acc[rt][0][r];
        int idx = cb + l15;                      // c = 0, cols ascending
        #pragma unroll
        for (int c = 1; c < 4; ++c) {
          const float vc = acc[rt][c][r];
          const int ic = cb + c * 16 + l15;
          if (vc > v) { v = vc; idx = ic; }      // strict > keeps lower col
        }
        DPP_RED_STEP(0x121)
        DPP_RED_STEP(0x122)
        DPP_RED_STEP(0x124)
        DPP_RED_STEP(0x128)
        if (l15 == 0) {
          const int lr = wv * 32 + rt * 16 + lhi * 4 + r;  // local row [0,128)
          tmS[lr][ct] = v;
          tiS[lr][ct] = (u16)idx;
        }
      }
  }
  __syncthreads();  // the only barrier: cross-wave flush

  // coalesced flush: per row 16 f32 (64 B) + 16 u16 (32 B)
  {
    const int r = t >> 1, half = t & 1;
    const int row = row0 + r;
    *reinterpret_cast<float4*>(&tm[(size_t)row * 64 + hs * 16 + half * 8]) =
        *reinterpret_cast<const float4*>(&tmS[r][half * 8]);
    *reinterpret_cast<float4*>(&tm[(size_t)row * 64 + hs * 16 + half * 8 + 4]) =
        *reinterpret_cast<const float4*>(&tmS[r][half * 8 + 4]);
  }
  if (t < SROWS) {
    const int row = row0 + t;
    *reinterpret_cast<uint4*>(&ti[(size_t)row * 64 + hs * 16]) =
        *reinterpret_cast<const uint4*>(&tiS[t][0]);
    *reinterpret_cast<uint4*>(&ti[(size_t)row * 64 + hs * 16 + 8]) =
        *reinterpret_cast<const uint4*>(&tiS[t][8]);
  }
}

// ---- K2: resolve (r12 verbatim): candidate list -> batch exact dots ----
__global__ __launch_bounds__(256) void vq_resolve(
    const float* __restrict__ X, const float* __restrict__ W,
    const float* __restrict__ tm, const u16* __restrict__ ti,
    float* __restrict__ outI, int K) {
  __shared__ float ftmp[256];
  __shared__ float xsqs[128];
  __shared__ u64 best64[128];
  __shared__ uint2 list[RCAP];
  __shared__ int cnt;

  const int t = threadIdx.x;
  const int row0 = blockIdx.x * 128;

  {
    const int r = t >> 1, half = t & 1;
    ftmp[t] = np_pw128_sq(X + (size_t)(row0 + r) * D_DIM + half * 128);
  }
  if (t == 0) cnt = 0;
  __syncthreads();
  if (t < 128) {
    xsqs[t] = __fadd_rn(ftmp[2 * t], ftmp[2 * t + 1]);
    best64[t] = 0xFFFFFFFFFFFFFFFFull;
  }
  __syncthreads();

  if (t < 128) {
    const int row = row0 + t;
    const float4* tm4 = reinterpret_cast<const float4*>(tm + (size_t)row * 64);
    float4 q[16];
    float rowmax = -3.4e38f;
    #pragma unroll
    for (int i = 0; i < 16; ++i) {
      q[i] = tm4[i];
      rowmax = fmaxf(rowmax, fmaxf(fmaxf(q[i].x, q[i].y), fmaxf(q[i].z, q[i].w)));
    }
    const float thr = rowmax - MARGIN;
    const u16* tir = ti + (size_t)row * 64;
    #pragma unroll
    for (int i = 0; i < 16; ++i) {
      #pragma unroll
      for (int j = 0; j < 4; ++j) {
        const float v = (j == 0) ? q[i].x : (j == 1) ? q[i].y
                      : (j == 2) ? q[i].z : q[i].w;
        if (v >= thr) {
          const int code = (int)tir[i * 4 + j] & (K - 1);
          const int idx = atomicAdd(&cnt, 1);
          if (idx < RCAP) {
            uint2 e; e.x = (u32)t; e.y = (u32)code;
            list[idx] = e;
          } else {
            const float a = exact_dot256(X + (size_t)row * D_DIM,
                                         W + (size_t)code * D_DIM);
            const float dist = __fsub_rn(xsqs[t], 2.0f * a);
            const u64 packed = ((u64)__float_as_uint(dist) << 32) | (u32)code;
            atomicMin(&best64[t], packed);
          }
        }
      }
    }
  }
  __syncthreads();

  int n = cnt; if (n > RCAP) n = RCAP;
  for (int i = t; i < n; i += 256) {
    const uint2 e = list[i];
    const float a = exact_dot256(X + (size_t)(row0 + (int)e.x) * D_DIM,
                                 W + (size_t)e.y * D_DIM);
    const float dist = __fsub_rn(xsqs[e.x], 2.0f * a);
    const u64 packed = ((u64)__float_as_uint(dist) << 32) | e.y;
    atomicMin(&best64[e.x], packed);
  }
  __syncthreads();

  if (t < 128) outI[row0 + t] = (float)(u32)(best64[t] & 0xFFFFFFFFull);
}

// ---- K3: gather W[k], qst, commit partials (r10 verbatim) ----
__global__ __launch_bounds__(256) void vq_gather(
    const float* __restrict__ X, const float* __restrict__ W,
    const float* __restrict__ outI, float* __restrict__ outQ,
    double* __restrict__ partials, int K) {
  __shared__ double dsum[256];
  const int t = threadIdx.x;
  const int r = t >> 1, half = t & 1;
  const int row = blockIdx.x * 128 + r;
  const int ix = (int)outI[row];

  double csum = 0.0;
  {
    const int k = ix & (K - 1);
    const float* xp = X + (size_t)row * D_DIM + half * 128;
    const float* wp = W + (size_t)k * D_DIM + half * 128;
    float* op = outQ + (size_t)row * D_DIM + half * 128;
    #pragma unroll 4
    for (int i = 0; i < 128; i += 4) {
      const float4 xv = *reinterpret_cast<const float4*>(xp + i);
      const float4 wv = *reinterpret_cast<const float4*>(wp + i);
      const float d0 = __fsub_rn(wv.x, xv.x), d1 = __fsub_rn(wv.y, xv.y);
      const float d2 = __fsub_rn(wv.z, xv.z), d3 = __fsub_rn(wv.w, xv.w);
      csum += (double)d0 * d0 + (double)d1 * d1 + (double)d2 * d2 + (double)d3 * d3;
      float4 o;
      o.x = __fadd_rn(xv.x, d0);
      o.y = __fadd_rn(xv.y, d1);
      o.z = __fadd_rn(xv.z, d2);
      o.w = __fadd_rn(xv.w, d3);
      *reinterpret_cast<float4*>(op + i) = o;
    }
  }
  dsum[t] = csum;
  __syncthreads();
  for (int s = 128; s > 0; s >>= 1) {
    if (t < s) dsum[t] += dsum[t + s];
    __syncthreads();
  }
  if (t == 0) partials[blockIdx.x] = dsum[0];
}

// ---- K4: finalize scalars ----
__global__ __launch_bounds__(256) void vq_finalize(
    const double* __restrict__ partials, float* __restrict__ outS,
    double invCount) {
  __shared__ double dsum[256];
  const int t = threadIdx.x;
  dsum[t] = partials[t];
  __syncthreads();
  for (int s = 128; s > 0; s >>= 1) {
    if (t < s) dsum[t] += dsum[t + s];
    __syncthreads();
  }
  if (t == 0) {
    const float m = (float)(dsum[0] * invCount);
    outS[0] = __fadd_rn(m, __fmul_rn(0.25f, m));  // (1+BETA)*mean
    outS[1] = 0.f;
  }
}

// ---- host-anomaly beacons ----
__global__ void zero_out_kernel(float* __restrict__ out, int n) {
  const int i = blockIdx.x * blockDim.x + threadIdx.x;
  const int stride = gridDim.x * blockDim.x;
  for (int j = i; j < n; j += stride) out[j] = 0.f;
}
__global__ void beacon_kernel(float* __restrict__ out, float v) {
  if (threadIdx.x == 0) out[0] = v;
}

extern "C" void kernel_launch(void* const* d_in, const int* in_sizes, int n_in,
                              void* d_out, int out_size, void* d_ws, size_t ws_size,
                              hipStream_t stream) {
  float* outF = (float*)d_out;

  float hostBeacon = 0.f;
  if (n_in != 2) hostBeacon = 21.f;
  else if (in_sizes[0] != 32768 * 256) hostBeacon = 23.f;
  else if (in_sizes[1] != 4096 * 256) hostBeacon = 25.f;
  else if (ws_size < 4096) hostBeacon = 27.f;
  else if (out_size != 32768 * 256 + 32768 + 2) hostBeacon = 29.f;

  if (hostBeacon != 0.f) {
    zero_out_kernel<<<dim3(2048), dim3(256), 0, stream>>>(outF, out_size);
    beacon_kernel<<<dim3(1), dim3(64), 0, stream>>>(outF, hostBeacon);
    return;
  }

  const float* X = (const float*)d_in[0];   // f32 [32768, 256]
  const float* W = (const float*)d_in[1];   // f32 [4096, 256]
  const int N = 32768, K = 4096;

  double* partials = (double*)d_ws;          // 256 doubles = 2048 B
  float* outQ = outF;                        // [N*256]  (32 MiB)
  float* outI = outQ + (size_t)N * D_DIM;    // [N]
  float* outS = outI + N;                    // [2]

  // stash inside outQ (consumed by sweep/resolve, then overwritten by gather):
  //   Wb bf16 [16Mi,18Mi) | tm f32 [18Mi,26Mi) | ti u16 [26Mi,30Mi)
  u16* Wb = (u16*)((char*)d_out + 16777216);
  float* tmv = (float*)((char*)d_out + 18874368);
  u16* tiv = (u16*)((char*)d_out + 27262976);

  cvtW_kernel<<<dim3(512), dim3(256), 0, stream>>>(W, Wb, K * D_DIM / 4);
  vq_sweep<<<dim3((N / SROWS) * SNS), dim3(256), 0, stream>>>(X, Wb, tmv, tiv, K);
  vq_resolve<<<dim3(N / 128), dim3(256), 0, stream>>>(X, W, tmv, tiv, outI, K);
  vq_gather<<<dim3(N / 128), dim3(256), 0, stream>>>(X, W, outI, outQ, partials, K);
  vq_finalize<<<dim3(1), dim3(256), 0, stream>>>(partials, outS,
                                                 1.0 / ((double)N * D_DIM));
}

// Round 17
// 303.807 us; speedup vs baseline: 1.4447x; 1.4447x over previous
//
#include <hip/hip_runtime.h>
#include <cstdint>
#include <cstddef>

#define D_DIM 256
#define NT 64            // codes per sweep tile
#define SROWS 128        // rows per sweep block (4 waves x 32 rows, rt=2)
#define SNS 2            // K splits in sweep (grid = 256*2 = 512)
#define MARGIN 1.3e-3f   // worst-case 2*eps bf16 bound (both-sided)
#define RCAP 2048        // resolve candidate list capacity per block

typedef unsigned int u32;
typedef unsigned short u16;
typedef unsigned long long u64;
typedef __attribute__((ext_vector_type(8))) short s16x8;
typedef __attribute__((ext_vector_type(4))) float f32x4;

static __device__ __forceinline__ u16 f2bf(float f) {
  u32 u = __float_as_uint(f);
  return (u16)((u + 0x7FFFu + ((u >> 16) & 1u)) >> 16);
}

// numpy pairwise_sum block for n=128 (bit-identical to rounds 6-16)
static __device__ __forceinline__ float np_pw128_sq(const float* __restrict__ p) {
  float r0, r1, r2, r3, r4, r5, r6, r7;
  {
    const float4 a = *reinterpret_cast<const float4*>(p);
    const float4 b = *reinterpret_cast<const float4*>(p + 4);
    r0 = __fmul_rn(a.x, a.x); r1 = __fmul_rn(a.y, a.y);
    r2 = __fmul_rn(a.z, a.z); r3 = __fmul_rn(a.w, a.w);
    r4 = __fmul_rn(b.x, b.x); r5 = __fmul_rn(b.y, b.y);
    r6 = __fmul_rn(b.z, b.z); r7 = __fmul_rn(b.w, b.w);
  }
  #pragma unroll
  for (int i = 8; i < 128; i += 8) {
    const float4 a = *reinterpret_cast<const float4*>(p + i);
    const float4 b = *reinterpret_cast<const float4*>(p + i + 4);
    r0 = __fadd_rn(r0, __fmul_rn(a.x, a.x));
    r1 = __fadd_rn(r1, __fmul_rn(a.y, a.y));
    r2 = __fadd_rn(r2, __fmul_rn(a.z, a.z));
    r3 = __fadd_rn(r3, __fmul_rn(a.w, a.w));
    r4 = __fadd_rn(r4, __fmul_rn(b.x, b.x));
    r5 = __fadd_rn(r5, __fmul_rn(b.y, b.y));
    r6 = __fadd_rn(r6, __fmul_rn(b.z, b.z));
    r7 = __fadd_rn(r7, __fmul_rn(b.w, b.w));
  }
  const float s01 = __fadd_rn(r0, r1);
  const float s23 = __fadd_rn(r2, r3);
  const float s45 = __fadd_rn(r4, r5);
  const float s67 = __fadd_rn(r6, r7);
  return __fadd_rn(__fadd_rn(s01, s23), __fadd_rn(s45, s67));
}

// exact r6-chain dot (sequential-d fmaf, bit-identical)
static __device__ __forceinline__ float exact_dot256(
    const float* __restrict__ xp, const float* __restrict__ wp) {
  float a = 0.f;
  #pragma unroll 8
  for (int d4 = 0; d4 < 64; ++d4) {
    const float4 xv = *reinterpret_cast<const float4*>(xp + d4 * 4);
    const float4 wv = *reinterpret_cast<const float4*>(wp + d4 * 4);
    a = fmaf(xv.x, wv.x, a);
    a = fmaf(xv.y, wv.y, a);
    a = fmaf(xv.z, wv.z, a);
    a = fmaf(xv.w, wv.w, a);
  }
  return a;
}

// ---- K0: f32 -> bf16 stash, W only (af built from f32 X in-sweep) ----
__global__ __launch_bounds__(256) void cvtW_kernel(
    const float* __restrict__ W, u16* __restrict__ Wb, int nw4) {
  const int tid = blockIdx.x * blockDim.x + threadIdx.x;
  const int stride = gridDim.x * blockDim.x;
  for (int g = tid; g < nw4; g += stride) {
    const float4 v = reinterpret_cast<const float4*>(W)[g];
    ushort4 o; o.x = f2bf(v.x); o.y = f2bf(v.y); o.z = f2bf(v.z); o.w = f2bf(v.w);
    reinterpret_cast<ushort4*>(Wb)[g] = o;
  }
}

// 16-lane (DPP row) max-reduce of (v, idx), ties -> lower idx. VALU-only.
#define DPP_RED_STEP(CTRL)                                                     \
  {                                                                            \
    const float ov = __uint_as_float((u32)__builtin_amdgcn_update_dpp(         \
        0, (int)__float_as_uint(v), CTRL, 0xF, 0xF, true));                    \
    const int oi = __builtin_amdgcn_update_dpp(0, idx, CTRL, 0xF, 0xF, true);  \
    if (ov > v || (ov == v && oi < idx)) { v = ov; idx = oi; }                 \
  }

// ---- K1: MFMA sweep, T14 async-STAGE split (deterministic reg staging):
// per tile: barrier -> ds_write staged regs -> ISSUE loads for ct+1 ->
// barrier -> MFMA. Staging L2 latency lands under the compute phase instead
// of serializing (r13/r15 pinned ~487 TF on the 2-barrier serial structure).
// af pinned via keep-alive (r15: VGPR 88 = af 64 + bf 16 + misc; acc in AGPR).
// grid = (N/SROWS)*SNS = 512, block 256.
__global__ __launch_bounds__(256, 2) void vq_sweep(
    const float* __restrict__ X, const u16* __restrict__ Wb,
    float* __restrict__ tm, u16* __restrict__ ti, int K) {
  __shared__ u16 Ws[NT * D_DIM];        // 32 KB, [kc8][code][8] subtiled
  __shared__ float tmS[SROWS][32];      // 16 KB per-tile top-1 values
  __shared__ u16 tiS[SROWS][32];        // 8 KB per-tile top-1 indices

  const int t = threadIdx.x;
  const int wv = t >> 6;
  const int lane = t & 63;
  const int l15 = lane & 15, lhi = lane >> 4;
  const int rb = blockIdx.x >> 1;      // SNS == 2
  const int hs = blockIdx.x & 1;
  const int row0 = rb * SROWS;
  const int wrow0 = row0 + wv * 32;
  const int c00 = hs * (K / SNS);      // 2048 codes per split

  // A fragments: wave's 32 rows x 256 d, f32 -> bf16 in-register, pinned
  s16x8 af[2][8];
  #pragma unroll
  for (int rt = 0; rt < 2; ++rt)
    #pragma unroll
    for (int kc = 0; kc < 8; ++kc) {
      const float* xp = X + (size_t)(wrow0 + rt * 16 + l15) * D_DIM + kc * 32 + lhi * 8;
      const float4 a = *reinterpret_cast<const float4*>(xp);
      const float4 b = *reinterpret_cast<const float4*>(xp + 4);
      s16x8 v;
      v[0] = (short)f2bf(a.x); v[1] = (short)f2bf(a.y);
      v[2] = (short)f2bf(a.z); v[3] = (short)f2bf(a.w);
      v[4] = (short)f2bf(b.x); v[5] = (short)f2bf(b.y);
      v[6] = (short)f2bf(b.z); v[7] = (short)f2bf(b.w);
      af[rt][kc] = v;
    }
  #pragma unroll
  for (int rt = 0; rt < 2; ++rt)
    #pragma unroll
    for (int kc = 0; kc < 8; ++kc)
      asm volatile("" : "+v"(af[rt][kc]));  // pin: cannot rematerialize

  // T14 stage registers + loader (code = t>>2 owns one code row, 8 uint4)
  const int code = t >> 2, k4 = t & 3;
  uint4 st[8];
  {
    const u16* wp = Wb + (size_t)(c00 + code) * D_DIM;
    #pragma unroll
    for (int kk = 0; kk < 8; ++kk)
      st[kk] = *reinterpret_cast<const uint4*>(wp + (kk * 4 + k4) * 8);
  }

  const int NTILES = K / SNS / NT;  // 32
  for (int ct = 0; ct < NTILES; ++ct) {
    __syncthreads();   // A: all waves done reading Ws (tile ct-1)
    // write staged tile ct into LDS
    #pragma unroll
    for (int kk = 0; kk < 8; ++kk) {
      const int kc8 = kk * 4 + k4;
      *reinterpret_cast<uint4*>(&Ws[(kc8 * NT + code) * 8]) = st[kk];
    }
    // issue loads for tile ct+1 (land during compute below)
    if (ct + 1 < NTILES) {
      const u16* wp = Wb + (size_t)(c00 + (ct + 1) * NT + code) * D_DIM;
      #pragma unroll
      for (int kk = 0; kk < 8; ++kk)
        st[kk] = *reinterpret_cast<const uint4*>(wp + (kk * 4 + k4) * 8);
    }
    __syncthreads();   // B: Ws (tile ct) visible to all waves

    const int cb = c00 + ct * NT;
    f32x4 acc[2][4];
    #pragma unroll
    for (int rt = 0; rt < 2; ++rt)
      #pragma unroll
      for (int c = 0; c < 4; ++c) acc[rt][c] = f32x4{0.f, 0.f, 0.f, 0.f};

    #pragma unroll
    for (int kc = 0; kc < 8; ++kc) {
      s16x8 bf[4];
      #pragma unroll
      for (int c = 0; c < 4; ++c)
        bf[c] = *reinterpret_cast<const s16x8*>(
            &Ws[((kc * 4 + lhi) * NT + c * 16 + l15) * 8]);
      #pragma unroll
      for (int c = 0; c < 4; ++c) {
        acc[0][c] = __builtin_amdgcn_mfma_f32_16x16x32_bf16(af[0][kc], bf[c], acc[0][c], 0, 0, 0);
        acc[1][c] = __builtin_amdgcn_mfma_f32_16x16x32_bf16(af[1][kc], bf[c], acc[1][c], 0, 0, 0);
      }
    }

    // per-row tile-top1 (value, idx) -> LDS (coalesced flush at end)
    #pragma unroll
    for (int rt = 0; rt < 2; ++rt)
      #pragma unroll
      for (int r = 0; r < 4; ++r) {
        float v = acc[rt][0][r];
        int idx = cb + l15;
        #pragma unroll
        for (int c = 1; c < 4; ++c) {
          const float vc = acc[rt][c][r];
          const int ic = cb + c * 16 + l15;
          if (vc > v) { v = vc; idx = ic; }      // strict > keeps lower col
        }
        DPP_RED_STEP(0x121)
        DPP_RED_STEP(0x122)
        DPP_RED_STEP(0x124)
        DPP_RED_STEP(0x128)
        if (l15 == 0) {
          const int lr = wv * 32 + rt * 16 + lhi * 4 + r;  // local row [0,128)
          tmS[lr][ct] = v;
          tiS[lr][ct] = (u16)idx;
        }
      }
  }
  __syncthreads();

  // coalesced flush: per row this block owns 32 entries (128 B f32 / 64 B u16)
  #pragma unroll
  for (int i = 0; i < 4; ++i) {
    const int idx = i * 256 + t;           // 1024 float4 total
    const int lr = idx >> 3, part = idx & 7;
    const int row = row0 + lr;
    *reinterpret_cast<float4*>(&tm[(size_t)row * 64 + hs * 32 + part * 4]) =
        *reinterpret_cast<const float4*>(&tmS[lr][part * 4]);
  }
  #pragma unroll
  for (int i = 0; i < 4; ++i) {
    const int idx = i * 256 + t;           // 1024 uint2 total
    const int lr = idx >> 3, part = idx & 7;
    const int row = row0 + lr;
    *reinterpret_cast<uint2*>(&ti[(size_t)row * 64 + hs * 32 + part * 4]) =
        *reinterpret_cast<const uint2*>(&tiS[lr][part * 4]);
  }
}

// ---- K2: resolve (r12 verbatim): candidate list -> batch exact dots ----
__global__ __launch_bounds__(256) void vq_resolve(
    const float* __restrict__ X, const float* __restrict__ W,
    const float* __restrict__ tm, const u16* __restrict__ ti,
    float* __restrict__ outI, int K) {
  __shared__ float ftmp[256];
  __shared__ float xsqs[128];
  __shared__ u64 best64[128];
  __shared__ uint2 list[RCAP];
  __shared__ int cnt;

  const int t = threadIdx.x;
  const int row0 = blockIdx.x * 128;

  {
    const int r = t >> 1, half = t & 1;
    ftmp[t] = np_pw128_sq(X + (size_t)(row0 + r) * D_DIM + half * 128);
  }
  if (t == 0) cnt = 0;
  __syncthreads();
  if (t < 128) {
    xsqs[t] = __fadd_rn(ftmp[2 * t], ftmp[2 * t + 1]);
    best64[t] = 0xFFFFFFFFFFFFFFFFull;
  }
  __syncthreads();

  if (t < 128) {
    const int row = row0 + t;
    const float4* tm4 = reinterpret_cast<const float4*>(tm + (size_t)row * 64);
    float4 q[16];
    float rowmax = -3.4e38f;
    #pragma unroll
    for (int i = 0; i < 16; ++i) {
      q[i] = tm4[i];
      rowmax = fmaxf(rowmax, fmaxf(fmaxf(q[i].x, q[i].y), fmaxf(q[i].z, q[i].w)));
    }
    const float thr = rowmax - MARGIN;
    const u16* tir = ti + (size_t)row * 64;
    #pragma unroll
    for (int i = 0; i < 16; ++i) {
      #pragma unroll
      for (int j = 0; j < 4; ++j) {
        const float v = (j == 0) ? q[i].x : (j == 1) ? q[i].y
                      : (j == 2) ? q[i].z : q[i].w;
        if (v >= thr) {
          const int code = (int)tir[i * 4 + j] & (K - 1);
          const int idx = atomicAdd(&cnt, 1);
          if (idx < RCAP) {
            uint2 e; e.x = (u32)t; e.y = (u32)code;
            list[idx] = e;
          } else {
            const float a = exact_dot256(X + (size_t)row * D_DIM,
                                         W + (size_t)code * D_DIM);
            const float dist = __fsub_rn(xsqs[t], 2.0f * a);
            const u64 packed = ((u64)__float_as_uint(dist) << 32) | (u32)code;
            atomicMin(&best64[t], packed);
          }
        }
      }
    }
  }
  __syncthreads();

  int n = cnt; if (n > RCAP) n = RCAP;
  for (int i = t; i < n; i += 256) {
    const uint2 e = list[i];
    const float a = exact_dot256(X + (size_t)(row0 + (int)e.x) * D_DIM,
                                 W + (size_t)e.y * D_DIM);
    const float dist = __fsub_rn(xsqs[e.x], 2.0f * a);
    const u64 packed = ((u64)__float_as_uint(dist) << 32) | e.y;
    atomicMin(&best64[e.x], packed);
  }
  __syncthreads();

  if (t < 128) outI[row0 + t] = (float)(u32)(best64[t] & 0xFFFFFFFFull);
}

// ---- K3: gather W[k], qst, commit partials (r10 verbatim) ----
__global__ __launch_bounds__(256) void vq_gather(
    const float* __restrict__ X, const float* __restrict__ W,
    const float* __restrict__ outI, float* __restrict__ outQ,
    double* __restrict__ partials, int K) {
  __shared__ double dsum[256];
  const int t = threadIdx.x;
  const int r = t >> 1, half = t & 1;
  const int row = blockIdx.x * 128 + r;
  const int ix = (int)outI[row];

  double csum = 0.0;
  {
    const int k = ix & (K - 1);
    const float* xp = X + (size_t)row * D_DIM + half * 128;
    const float* wp = W + (size_t)k * D_DIM + half * 128;
    float* op = outQ + (size_t)row * D_DIM + half * 128;
    #pragma unroll 4
    for (int i = 0; i < 128; i += 4) {
      const float4 xv = *reinterpret_cast<const float4*>(xp + i);
      const float4 wv = *reinterpret_cast<const float4*>(wp + i);
      const float d0 = __fsub_rn(wv.x, xv.x), d1 = __fsub_rn(wv.y, xv.y);
      const float d2 = __fsub_rn(wv.z, xv.z), d3 = __fsub_rn(wv.w, xv.w);
      csum += (double)d0 * d0 + (double)d1 * d1 + (double)d2 * d2 + (double)d3 * d3;
      float4 o;
      o.x = __fadd_rn(xv.x, d0);
      o.y = __fadd_rn(xv.y, d1);
      o.z = __fadd_rn(xv.z, d2);
      o.w = __fadd_rn(xv.w, d3);
      *reinterpret_cast<float4*>(op + i) = o;
    }
  }
  dsum[t] = csum;
  __syncthreads();
  for (int s = 128; s > 0; s >>= 1) {
    if (t < s) dsum[t] += dsum[t + s];
    __syncthreads();
  }
  if (t == 0) partials[blockIdx.x] = dsum[0];
}

// ---- K4: finalize scalars ----
__global__ __launch_bounds__(256) void vq_finalize(
    const double* __restrict__ partials, float* __restrict__ outS,
    double invCount) {
  __shared__ double dsum[256];
  const int t = threadIdx.x;
  dsum[t] = partials[t];
  __syncthreads();
  for (int s = 128; s > 0; s >>= 1) {
    if (t < s) dsum[t] += dsum[t + s];
    __syncthreads();
  }
  if (t == 0) {
    const float m = (float)(dsum[0] * invCount);
    outS[0] = __fadd_rn(m, __fmul_rn(0.25f, m));  // (1+BETA)*mean
    outS[1] = 0.f;
  }
}

// ---- host-anomaly beacons ----
__global__ void zero_out_kernel(float* __restrict__ out, int n) {
  const int i = blockIdx.x * blockDim.x + threadIdx.x;
  const int stride = gridDim.x * blockDim.x;
  for (int j = i; j < n; j += stride) out[j] = 0.f;
}
__global__ void beacon_kernel(float* __restrict__ out, float v) {
  if (threadIdx.x == 0) out[0] = v;
}

extern "C" void kernel_launch(void* const* d_in, const int* in_sizes, int n_in,
                              void* d_out, int out_size, void* d_ws, size_t ws_size,
                              hipStream_t stream) {
  float* outF = (float*)d_out;

  float hostBeacon = 0.f;
  if (n_in != 2) hostBeacon = 21.f;
  else if (in_sizes[0] != 32768 * 256) hostBeacon = 23.f;
  else if (in_sizes[1] != 4096 * 256) hostBeacon = 25.f;
  else if (ws_size < 4096) hostBeacon = 27.f;
  else if (out_size != 32768 * 256 + 32768 + 2) hostBeacon = 29.f;

  if (hostBeacon != 0.f) {
    zero_out_kernel<<<dim3(2048), dim3(256), 0, stream>>>(outF, out_size);
    beacon_kernel<<<dim3(1), dim3(64), 0, stream>>>(outF, hostBeacon);
    return;
  }

  const float* X = (const float*)d_in[0];   // f32 [32768, 256]
  const float* W = (const float*)d_in[1];   // f32 [4096, 256]
  const int N = 32768, K = 4096;

  double* partials = (double*)d_ws;          // 256 doubles = 2048 B
  float* outQ = outF;                        // [N*256]  (32 MiB)
  float* outI = outQ + (size_t)N * D_DIM;    // [N]
  float* outS = outI + N;                    // [2]

  // stash inside outQ (consumed by sweep/resolve, then overwritten by gather):
  //   Wb bf16 [16Mi,18Mi) | tm f32 [18Mi,26Mi) | ti u16 [26Mi,30Mi)
  u16* Wb = (u16*)((char*)d_out + 16777216);
  float* tmv = (float*)((char*)d_out + 18874368);
  u16* tiv = (u16*)((char*)d_out + 27262976);

  cvtW_kernel<<<dim3(512), dim3(256), 0, stream>>>(W, Wb, K * D_DIM / 4);
  vq_sweep<<<dim3((N / SROWS) * SNS), dim3(256), 0, stream>>>(X, Wb, tmv, tiv, K);
  vq_resolve<<<dim3(N / 128), dim3(256), 0, stream>>>(X, W, tmv, tiv, outI, K);
  vq_gather<<<dim3(N / 128), dim3(256), 0, stream>>>(X, W, outI, outQ, partials, K);
  vq_finalize<<<dim3(1), dim3(256), 0, stream>>>(partials, outS,
                                                 1.0 / ((double)N * D_DIM));
}

// Round 18
// 233.510 us; speedup vs baseline: 1.8796x; 1.3010x over previous
//
#include <hip/hip_runtime.h>
#include <cstdint>
#include <cstddef>

#define D_DIM 256
#define NT 64            // codes per sweep tile
#define SROWS 128        // rows per sweep block (4 waves x 32 rows, rt=2)
#define SNS 8            // K splits in sweep (grid = 256*8 = 2048)
#define MARGIN 1.3e-3f   // worst-case 2*eps bf16 bound (both-sided)
#define RCAP 2048        // resolve candidate list capacity per block

typedef unsigned int u32;
typedef unsigned short u16;
typedef unsigned long long u64;
typedef __attribute__((ext_vector_type(8))) short s16x8;
typedef __attribute__((ext_vector_type(4))) float f32x4;

static __device__ __forceinline__ u16 f2bf(float f) {
  u32 u = __float_as_uint(f);
  return (u16)((u + 0x7FFFu + ((u >> 16) & 1u)) >> 16);
}

// numpy pairwise_sum block for n=128 (bit-identical to rounds 6-17)
static __device__ __forceinline__ float np_pw128_sq(const float* __restrict__ p) {
  float r0, r1, r2, r3, r4, r5, r6, r7;
  {
    const float4 a = *reinterpret_cast<const float4*>(p);
    const float4 b = *reinterpret_cast<const float4*>(p + 4);
    r0 = __fmul_rn(a.x, a.x); r1 = __fmul_rn(a.y, a.y);
    r2 = __fmul_rn(a.z, a.z); r3 = __fmul_rn(a.w, a.w);
    r4 = __fmul_rn(b.x, b.x); r5 = __fmul_rn(b.y, b.y);
    r6 = __fmul_rn(b.z, b.z); r7 = __fmul_rn(b.w, b.w);
  }
  #pragma unroll
  for (int i = 8; i < 128; i += 8) {
    const float4 a = *reinterpret_cast<const float4*>(p + i);
    const float4 b = *reinterpret_cast<const float4*>(p + i + 4);
    r0 = __fadd_rn(r0, __fmul_rn(a.x, a.x));
    r1 = __fadd_rn(r1, __fmul_rn(a.y, a.y));
    r2 = __fadd_rn(r2, __fmul_rn(a.z, a.z));
    r3 = __fadd_rn(r3, __fmul_rn(a.w, a.w));
    r4 = __fadd_rn(r4, __fmul_rn(b.x, b.x));
    r5 = __fadd_rn(r5, __fmul_rn(b.y, b.y));
    r6 = __fadd_rn(r6, __fmul_rn(b.z, b.z));
    r7 = __fadd_rn(r7, __fmul_rn(b.w, b.w));
  }
  const float s01 = __fadd_rn(r0, r1);
  const float s23 = __fadd_rn(r2, r3);
  const float s45 = __fadd_rn(r4, r5);
  const float s67 = __fadd_rn(r6, r7);
  return __fadd_rn(__fadd_rn(s01, s23), __fadd_rn(s45, s67));
}

// exact r6-chain dot (sequential-d fmaf, bit-identical)
static __device__ __forceinline__ float exact_dot256(
    const float* __restrict__ xp, const float* __restrict__ wp) {
  float a = 0.f;
  #pragma unroll 8
  for (int d4 = 0; d4 < 64; ++d4) {
    const float4 xv = *reinterpret_cast<const float4*>(xp + d4 * 4);
    const float4 wv = *reinterpret_cast<const float4*>(wp + d4 * 4);
    a = fmaf(xv.x, wv.x, a);
    a = fmaf(xv.y, wv.y, a);
    a = fmaf(xv.z, wv.z, a);
    a = fmaf(xv.w, wv.w, a);
  }
  return a;
}

// ---- K0: f32 -> bf16 stash, W only (af built from f32 X in-sweep) ----
__global__ __launch_bounds__(256) void cvtW_kernel(
    const float* __restrict__ W, u16* __restrict__ Wb, int nw4) {
  const int tid = blockIdx.x * blockDim.x + threadIdx.x;
  const int stride = gridDim.x * blockDim.x;
  for (int g = tid; g < nw4; g += stride) {
    const float4 v = reinterpret_cast<const float4*>(W)[g];
    ushort4 o; o.x = f2bf(v.x); o.y = f2bf(v.y); o.z = f2bf(v.z); o.w = f2bf(v.w);
    reinterpret_cast<ushort4*>(Wb)[g] = o;
  }
}

// 16-lane (DPP row) max-reduce of (v, idx), ties -> lower idx. VALU-only.
#define DPP_RED_STEP(CTRL)                                                     \
  {                                                                            \
    const float ov = __uint_as_float((u32)__builtin_amdgcn_update_dpp(         \
        0, (int)__float_as_uint(v), CTRL, 0xF, 0xF, true));                    \
    const int oi = __builtin_amdgcn_update_dpp(0, idx, CTRL, 0xF, 0xF, true);  \
    if (ov > v || (ov == v && oi < idx)) { v = ov; idx = oi; }                 \
  }

// ---- K1: MFMA sweep, 4-blocks/CU occupancy variant. Small LDS footprint
// (Ws 32K + tmS 4K + tiS 2K = 38.9 KB) -> 4 resident blocks per CU so one
// block's stage/barrier latency hides under three others' MFMA phases
// (r13/r15/r17 all latency-bound at 2 blocks/CU, MfmaUtil 14-20%).
// Simple r13-proven staging; af from f32 X (r16/r17-proven numerics).
// grid = (N/SROWS)*SNS = 2048, block 256.
__global__ __launch_bounds__(256, 4) void vq_sweep(
    const float* __restrict__ X, const u16* __restrict__ Wb,
    float* __restrict__ tm, u16* __restrict__ ti, int K) {
  __shared__ u16 Ws[NT * D_DIM];        // 32 KB, [kc8][code][8] subtiled
  __shared__ float tmS[SROWS][8];       // 4 KB per-tile top-1 values
  __shared__ u16 tiS[SROWS][8];         // 2 KB per-tile top-1 indices

  const int t = threadIdx.x;
  const int wv = t >> 6;
  const int lane = t & 63;
  const int l15 = lane & 15, lhi = lane >> 4;
  const int rb = blockIdx.x >> 3;      // SNS == 8
  const int hs = blockIdx.x & 7;
  const int row0 = rb * SROWS;
  const int wrow0 = row0 + wv * 32;
  const int c00 = hs * (K / SNS);      // 512 codes per split

  // A fragments: wave's 32 rows x 256 d, f32 -> bf16 in-register, pinned
  s16x8 af[2][8];
  #pragma unroll
  for (int rt = 0; rt < 2; ++rt)
    #pragma unroll
    for (int kc = 0; kc < 8; ++kc) {
      const float* xp = X + (size_t)(wrow0 + rt * 16 + l15) * D_DIM + kc * 32 + lhi * 8;
      const float4 a = *reinterpret_cast<const float4*>(xp);
      const float4 b = *reinterpret_cast<const float4*>(xp + 4);
      s16x8 v;
      v[0] = (short)f2bf(a.x); v[1] = (short)f2bf(a.y);
      v[2] = (short)f2bf(a.z); v[3] = (short)f2bf(a.w);
      v[4] = (short)f2bf(b.x); v[5] = (short)f2bf(b.y);
      v[6] = (short)f2bf(b.z); v[7] = (short)f2bf(b.w);
      af[rt][kc] = v;
    }
  #pragma unroll
  for (int rt = 0; rt < 2; ++rt)
    #pragma unroll
    for (int kc = 0; kc < 8; ++kc)
      asm volatile("" : "+v"(af[rt][kc]));  // pin: cannot rematerialize

  const int code = t >> 2, k4 = t & 3;
  const int NTILES = K / SNS / NT;  // 8
  for (int ct = 0; ct < NTILES; ++ct) {
    __syncthreads();   // all waves done reading Ws (tile ct-1)
    {  // stage W tile (r13-proven reg round-trip): codes c00+ct*64 .. +63
      const u16* wp = Wb + (size_t)(c00 + ct * NT + code) * D_DIM;
      #pragma unroll
      for (int kk = 0; kk < 8; ++kk) {
        const int kc8 = kk * 4 + k4;
        *reinterpret_cast<uint4*>(&Ws[(kc8 * NT + code) * 8]) =
            *reinterpret_cast<const uint4*>(wp + kc8 * 8);
      }
    }
    __syncthreads();   // Ws (tile ct) visible to all waves

    const int cb = c00 + ct * NT;
    f32x4 acc[2][4];
    #pragma unroll
    for (int rt = 0; rt < 2; ++rt)
      #pragma unroll
      for (int c = 0; c < 4; ++c) acc[rt][c] = f32x4{0.f, 0.f, 0.f, 0.f};

    #pragma unroll
    for (int kc = 0; kc < 8; ++kc) {
      s16x8 bf[4];
      #pragma unroll
      for (int c = 0; c < 4; ++c)
        bf[c] = *reinterpret_cast<const s16x8*>(
            &Ws[((kc * 4 + lhi) * NT + c * 16 + l15) * 8]);
      #pragma unroll
      for (int c = 0; c < 4; ++c) {
        acc[0][c] = __builtin_amdgcn_mfma_f32_16x16x32_bf16(af[0][kc], bf[c], acc[0][c], 0, 0, 0);
        acc[1][c] = __builtin_amdgcn_mfma_f32_16x16x32_bf16(af[1][kc], bf[c], acc[1][c], 0, 0, 0);
      }
    }

    // per-row tile-top1 (value, idx) -> LDS (coalesced flush at end)
    #pragma unroll
    for (int rt = 0; rt < 2; ++rt)
      #pragma unroll
      for (int r = 0; r < 4; ++r) {
        float v = acc[rt][0][r];
        int idx = cb + l15;
        #pragma unroll
        for (int c = 1; c < 4; ++c) {
          const float vc = acc[rt][c][r];
          const int ic = cb + c * 16 + l15;
          if (vc > v) { v = vc; idx = ic; }      // strict > keeps lower col
        }
        DPP_RED_STEP(0x121)
        DPP_RED_STEP(0x122)
        DPP_RED_STEP(0x124)
        DPP_RED_STEP(0x128)
        if (l15 == 0) {
          const int lr = wv * 32 + rt * 16 + lhi * 4 + r;  // local row [0,128)
          tmS[lr][ct] = v;
          tiS[lr][ct] = (u16)idx;
        }
      }
  }
  __syncthreads();

  // coalesced flush: per row this block owns 8 entries (32 B f32 / 16 B u16)
  {
    const int lr = t >> 1, half = t & 1;     // 256 threads = 128 rows x 2
    const int row = row0 + lr;
    *reinterpret_cast<float4*>(&tm[(size_t)row * 64 + hs * 8 + half * 4]) =
        *reinterpret_cast<const float4*>(&tmS[lr][half * 4]);
  }
  if (t < SROWS) {
    const int row = row0 + t;
    *reinterpret_cast<uint4*>(&ti[(size_t)row * 64 + hs * 8]) =
        *reinterpret_cast<const uint4*>(&tiS[t][0]);
  }
}

// ---- K2: resolve (r12 verbatim): candidate list -> batch exact dots ----
__global__ __launch_bounds__(256) void vq_resolve(
    const float* __restrict__ X, const float* __restrict__ W,
    const float* __restrict__ tm, const u16* __restrict__ ti,
    float* __restrict__ outI, int K) {
  __shared__ float ftmp[256];
  __shared__ float xsqs[128];
  __shared__ u64 best64[128];
  __shared__ uint2 list[RCAP];
  __shared__ int cnt;

  const int t = threadIdx.x;
  const int row0 = blockIdx.x * 128;

  {
    const int r = t >> 1, half = t & 1;
    ftmp[t] = np_pw128_sq(X + (size_t)(row0 + r) * D_DIM + half * 128);
  }
  if (t == 0) cnt = 0;
  __syncthreads();
  if (t < 128) {
    xsqs[t] = __fadd_rn(ftmp[2 * t], ftmp[2 * t + 1]);
    best64[t] = 0xFFFFFFFFFFFFFFFFull;
  }
  __syncthreads();

  if (t < 128) {
    const int row = row0 + t;
    const float4* tm4 = reinterpret_cast<const float4*>(tm + (size_t)row * 64);
    float4 q[16];
    float rowmax = -3.4e38f;
    #pragma unroll
    for (int i = 0; i < 16; ++i) {
      q[i] = tm4[i];
      rowmax = fmaxf(rowmax, fmaxf(fmaxf(q[i].x, q[i].y), fmaxf(q[i].z, q[i].w)));
    }
    const float thr = rowmax - MARGIN;
    const u16* tir = ti + (size_t)row * 64;
    #pragma unroll
    for (int i = 0; i < 16; ++i) {
      #pragma unroll
      for (int j = 0; j < 4; ++j) {
        const float v = (j == 0) ? q[i].x : (j == 1) ? q[i].y
                      : (j == 2) ? q[i].z : q[i].w;
        if (v >= thr) {
          const int code = (int)tir[i * 4 + j] & (K - 1);
          const int idx = atomicAdd(&cnt, 1);
          if (idx < RCAP) {
            uint2 e; e.x = (u32)t; e.y = (u32)code;
            list[idx] = e;
          } else {
            const float a = exact_dot256(X + (size_t)row * D_DIM,
                                         W + (size_t)code * D_DIM);
            const float dist = __fsub_rn(xsqs[t], 2.0f * a);
            const u64 packed = ((u64)__float_as_uint(dist) << 32) | (u32)code;
            atomicMin(&best64[t], packed);
          }
        }
      }
    }
  }
  __syncthreads();

  int n = cnt; if (n > RCAP) n = RCAP;
  for (int i = t; i < n; i += 256) {
    const uint2 e = list[i];
    const float a = exact_dot256(X + (size_t)(row0 + (int)e.x) * D_DIM,
                                 W + (size_t)e.y * D_DIM);
    const float dist = __fsub_rn(xsqs[e.x], 2.0f * a);
    const u64 packed = ((u64)__float_as_uint(dist) << 32) | e.y;
    atomicMin(&best64[e.x], packed);
  }
  __syncthreads();

  if (t < 128) outI[row0 + t] = (float)(u32)(best64[t] & 0xFFFFFFFFull);
}

// ---- K3: gather W[k], qst, commit partials (r10 verbatim) ----
__global__ __launch_bounds__(256) void vq_gather(
    const float* __restrict__ X, const float* __restrict__ W,
    const float* __restrict__ outI, float* __restrict__ outQ,
    double* __restrict__ partials, int K) {
  __shared__ double dsum[256];
  const int t = threadIdx.x;
  const int r = t >> 1, half = t & 1;
  const int row = blockIdx.x * 128 + r;
  const int ix = (int)outI[row];

  double csum = 0.0;
  {
    const int k = ix & (K - 1);
    const float* xp = X + (size_t)row * D_DIM + half * 128;
    const float* wp = W + (size_t)k * D_DIM + half * 128;
    float* op = outQ + (size_t)row * D_DIM + half * 128;
    #pragma unroll 4
    for (int i = 0; i < 128; i += 4) {
      const float4 xv = *reinterpret_cast<const float4*>(xp + i);
      const float4 wv = *reinterpret_cast<const float4*>(wp + i);
      const float d0 = __fsub_rn(wv.x, xv.x), d1 = __fsub_rn(wv.y, xv.y);
      const float d2 = __fsub_rn(wv.z, xv.z), d3 = __fsub_rn(wv.w, xv.w);
      csum += (double)d0 * d0 + (double)d1 * d1 + (double)d2 * d2 + (double)d3 * d3;
      float4 o;
      o.x = __fadd_rn(xv.x, d0);
      o.y = __fadd_rn(xv.y, d1);
      o.z = __fadd_rn(xv.z, d2);
      o.w = __fadd_rn(xv.w, d3);
      *reinterpret_cast<float4*>(op + i) = o;
    }
  }
  dsum[t] = csum;
  __syncthreads();
  for (int s = 128; s > 0; s >>= 1) {
    if (t < s) dsum[t] += dsum[t + s];
    __syncthreads();
  }
  if (t == 0) partials[blockIdx.x] = dsum[0];
}

// ---- K4: finalize scalars ----
__global__ __launch_bounds__(256) void vq_finalize(
    const double* __restrict__ partials, float* __restrict__ outS,
    double invCount) {
  __shared__ double dsum[256];
  const int t = threadIdx.x;
  dsum[t] = partials[t];
  __syncthreads();
  for (int s = 128; s > 0; s >>= 1) {
    if (t < s) dsum[t] += dsum[t + s];
    __syncthreads();
  }
  if (t == 0) {
    const float m = (float)(dsum[0] * invCount);
    outS[0] = __fadd_rn(m, __fmul_rn(0.25f, m));  // (1+BETA)*mean
    outS[1] = 0.f;
  }
}

// ---- host-anomaly beacons ----
__global__ void zero_out_kernel(float* __restrict__ out, int n) {
  const int i = blockIdx.x * blockDim.x + threadIdx.x;
  const int stride = gridDim.x * blockDim.x;
  for (int j = i; j < n; j += stride) out[j] = 0.f;
}
__global__ void beacon_kernel(float* __restrict__ out, float v) {
  if (threadIdx.x == 0) out[0] = v;
}

extern "C" void kernel_launch(void* const* d_in, const int* in_sizes, int n_in,
                              void* d_out, int out_size, void* d_ws, size_t ws_size,
                              hipStream_t stream) {
  float* outF = (float*)d_out;

  float hostBeacon = 0.f;
  if (n_in != 2) hostBeacon = 21.f;
  else if (in_sizes[0] != 32768 * 256) hostBeacon = 23.f;
  else if (in_sizes[1] != 4096 * 256) hostBeacon = 25.f;
  else if (ws_size < 4096) hostBeacon = 27.f;
  else if (out_size != 32768 * 256 + 32768 + 2) hostBeacon = 29.f;

  if (hostBeacon != 0.f) {
    zero_out_kernel<<<dim3(2048), dim3(256), 0, stream>>>(outF, out_size);
    beacon_kernel<<<dim3(1), dim3(64), 0, stream>>>(outF, hostBeacon);
    return;
  }

  const float* X = (const float*)d_in[0];   // f32 [32768, 256]
  const float* W = (const float*)d_in[1];   // f32 [4096, 256]
  const int N = 32768, K = 4096;

  double* partials = (double*)d_ws;          // 256 doubles = 2048 B
  float* outQ = outF;                        // [N*256]  (32 MiB)
  float* outI = outQ + (size_t)N * D_DIM;    // [N]
  float* outS = outI + N;                    // [2]

  // stash inside outQ (consumed by sweep/resolve, then overwritten by gather):
  //   Wb bf16 [16Mi,18Mi) | tm f32 [18Mi,26Mi) | ti u16 [26Mi,30Mi)
  u16* Wb = (u16*)((char*)d_out + 16777216);
  float* tmv = (float*)((char*)d_out + 18874368);
  u16* tiv = (u16*)((char*)d_out + 27262976);

  cvtW_kernel<<<dim3(512), dim3(256), 0, stream>>>(W, Wb, K * D_DIM / 4);
  vq_sweep<<<dim3((N / SROWS) * SNS), dim3(256), 0, stream>>>(X, Wb, tmv, tiv, K);
  vq_resolve<<<dim3(N / 128), dim3(256), 0, stream>>>(X, W, tmv, tiv, outI, K);
  vq_gather<<<dim3(N / 128), dim3(256), 0, stream>>>(X, W, outI, outQ, partials, K);
  vq_finalize<<<dim3(1), dim3(256), 0, stream>>>(partials, outS,
                                                 1.0 / ((double)N * D_DIM));
}